// Round 1
// baseline (2109.446 us; speedup 1.0000x reference)
//
#include <hip/hip_runtime.h>

#define G 3
#define K 40
#define S 1024
#define NB 32
#define CH 30
#define T 16384
#define TP 4096
#define M 131072           // NB*TP
#define CT (CH*T)          // 491520
#define OUT_Q (NB*CH*T)    // 15728640

// ---------------- prep: e2h[g][s] = 0.5*||codebook[g][s]||^2 (fp32), zero loss accum
__global__ void vq_prep_kernel(const float* __restrict__ cb, float* __restrict__ e2h,
                               double* __restrict__ loss) {
    int i = blockIdx.x * blockDim.x + threadIdx.x;   // [0, G*S)
    if (i == 0) *loss = 0.0;
    if (i < G * S) {
        const float* c = cb + (size_t)i * K;
        float s = 0.f;
        #pragma unroll
        for (int k = 0; k < K; ++k) s = fmaf(c[k], c[k], s);
        e2h[i] = 0.5f * s;
    }
}

// ---------------- main: per-thread brute-force argmin + fp64 near-tie recheck
__global__ __launch_bounds__(256) void vq_main_kernel(
        const float* __restrict__ z, const float* __restrict__ cb,
        const float* __restrict__ e2h, float* __restrict__ out,
        double* __restrict__ loss) {
    __shared__ double red[256];

    const int b  = blockIdx.x;
    const int g  = b >> 9;                       // 512 blocks per group
    const int m  = ((b & 511) << 8) + threadIdx.x;
    const int n  = m >> 12;                      // / TP
    const int tp = m & 4095;                     // % TP

    const float* zp = z + (size_t)n * CT + (size_t)g * K * TP + tp;
    float x[K];
    #pragma unroll
    for (int k = 0; k < K; ++k) x[k] = zp[(size_t)k * TP];

    const float4* cb4 = reinterpret_cast<const float4*>(cb + (size_t)g * S * K);
    const float*  e2g = e2h + g * S;

    float v1 = 3.4e38f, v2 = 3.4e38f;
    int   s1 = 0,       s2 = 0;

    #pragma unroll 2
    for (int s = 0; s < S; ++s) {
        const float4* cw = cb4 + s * 10;
        float d0 = 0.f, d1 = 0.f, d2 = 0.f, d3 = 0.f;
        #pragma unroll
        for (int i = 0; i < 10; ++i) {
            float4 c = cw[i];
            d0 = fmaf(c.x, x[4*i+0], d0);
            d1 = fmaf(c.y, x[4*i+1], d1);
            d2 = fmaf(c.z, x[4*i+2], d2);
            d3 = fmaf(c.w, x[4*i+3], d3);
        }
        float score = e2g[s] - ((d0 + d1) + (d2 + d3));   // 0.5||e||^2 - x.e
        if (score < v1)      { v2 = v1; s2 = s1; v1 = score; s1 = s; }
        else if (score < v2) { v2 = score; s2 = s; }
    }

    // fp64 recheck when fp32 gap is within the rounding-uncertainty margin
    if (v2 - v1 < 1e-3f) {
        const float* c1 = cb + ((size_t)g * S + s1) * K;
        const float* c2 = cb + ((size_t)g * S + s2) * K;
        double t1 = 0.0, t2 = 0.0, e1 = 0.0, e2 = 0.0;
        #pragma unroll
        for (int k = 0; k < K; ++k) {
            double xk = (double)x[k];
            double a  = (double)c1[k];
            double bb = (double)c2[k];
            t1 = fma(a,  xk, t1);  e1 = fma(a,  a,  e1);
            t2 = fma(bb, xk, t2);  e2 = fma(bb, bb, e2);
        }
        double sc1 = 0.5 * e1 - t1;
        double sc2 = 0.5 * e2 - t2;
        if (sc2 < sc1 || (sc2 == sc1 && s2 < s1)) s1 = s2;
    }

    // gather winning codeword -> output; fp64 loss partial (last group only)
    const float* cw = cb + ((size_t)g * S + s1) * K;
    float* op = out + (size_t)n * CT + (size_t)g * K * TP + tp;
    double lsum = 0.0;
    #pragma unroll
    for (int k = 0; k < K; ++k) {
        float q = cw[k];
        op[(size_t)k * TP] = q;
        double d = (double)q - (double)x[k];
        lsum = fma(d, d, lsum);
    }

    if (g == 2) {
        red[threadIdx.x] = lsum;
        __syncthreads();
        for (int off = 128; off > 0; off >>= 1) {
            if (threadIdx.x < off) red[threadIdx.x] += red[threadIdx.x + off];
            __syncthreads();
        }
        if (threadIdx.x == 0) atomicAdd(loss, red[0]);
    }
}

// ---------------- finalize: scalar loss
__global__ void vq_fin_kernel(const double* __restrict__ loss, float* __restrict__ out) {
    out[OUT_Q] = (float)(0.25 * (*loss) / (double)((long long)M * K));
}

extern "C" void kernel_launch(void* const* d_in, const int* in_sizes, int n_in,
                              void* d_out, int out_size, void* d_ws, size_t ws_size,
                              hipStream_t stream) {
    const float* z  = (const float*)d_in[0];
    const float* cb = (const float*)d_in[1];
    float* out = (float*)d_out;

    double* loss = (double*)d_ws;
    float*  e2h  = (float*)((char*)d_ws + 64);

    vq_prep_kernel<<<dim3((G * S + 255) / 256), dim3(256), 0, stream>>>(cb, e2h, loss);
    vq_main_kernel<<<dim3(G * (M / 256)), dim3(256), 0, stream>>>(z, cb, e2h, out, loss);
    vq_fin_kernel<<<dim3(1), dim3(1), 0, stream>>>(loss, out);
}

// Round 2
// 828.108 us; speedup vs baseline: 2.5473x; 2.5473x over previous
//
#include <hip/hip_runtime.h>

#define G 3
#define K 40
#define S 1024
#define NB 32
#define CH 30
#define T 16384
#define TP 4096
#define M 131072           // NB*TP
#define CT (CH*T)          // 491520
#define OUT_Q (NB*CH*T)    // 15728640

// ---------------- prep: e2h[g][s] = 0.5*||codebook[g][s]||^2 (fp32), zero loss accum
__global__ void vq_prep_kernel(const float* __restrict__ cb, float* __restrict__ e2h,
                               double* __restrict__ loss) {
    int i = blockIdx.x * blockDim.x + threadIdx.x;   // [0, G*S)
    if (i == 0) *loss = 0.0;
    if (i < G * S) {
        const float* c = cb + (size_t)i * K;
        float s = 0.f;
        #pragma unroll
        for (int k = 0; k < K; ++k) s = fmaf(c[k], c[k], s);
        e2h[i] = 0.5f * s;
    }
}

// ---------------- main: 2 queries/thread, double-buffered codeword prefetch
__global__ __launch_bounds__(256) void vq_main_kernel(
        const float* __restrict__ z, const float* __restrict__ cb,
        const float* __restrict__ e2h, float* __restrict__ out,
        double* __restrict__ loss) {
    __shared__ double red[256];

    const int b    = blockIdx.x;
    const int g    = b >> 8;                                // 256 blocks per group
    const int pair = ((b & 255) << 8) + threadIdx.x;        // [0, M/2)
    const int m    = pair << 1;                             // first query index
    const int n    = m >> 12;                               // / TP
    const int tp   = m & 4095;                              // % TP (even)

    const float2* zp2 = reinterpret_cast<const float2*>(
        z + (size_t)n * CT + (size_t)g * K * TP + tp);
    float2 x[K];                                            // x[k] = {query0[k], query1[k]}
    #pragma unroll
    for (int k = 0; k < K; ++k) x[k] = zp2[k * (TP / 2)];

    const float4* cb4 = reinterpret_cast<const float4*>(cb + (size_t)g * S * K);
    const float*  e2g = e2h + g * S;

    float4 A[10], B[10];
    #pragma unroll
    for (int i = 0; i < 10; ++i) A[i] = cb4[i];
    float eA = e2g[0], eB;

    float v1a = 3.4e38f, v2a = 3.4e38f, v1b = 3.4e38f, v2b = 3.4e38f;
    int   s1a = 0, s2a = 0, s1b = 0, s2b = 0;

    for (int s = 0; s < S; s += 2) {
        // prefetch codeword s+1 into B
        const float4* pB = cb4 + (s + 1) * 10;
        #pragma unroll
        for (int i = 0; i < 10; ++i) B[i] = pB[i];
        eB = e2g[s + 1];

        // compute with A (codeword s)
        {
            float a0 = 0.f, a1 = 0.f, b0 = 0.f, b1 = 0.f;
            #pragma unroll
            for (int i = 0; i < 10; ++i) {
                float4 c = A[i];
                a0 = fmaf(c.x, x[4*i+0].x, a0);  b0 = fmaf(c.x, x[4*i+0].y, b0);
                a1 = fmaf(c.y, x[4*i+1].x, a1);  b1 = fmaf(c.y, x[4*i+1].y, b1);
                a0 = fmaf(c.z, x[4*i+2].x, a0);  b0 = fmaf(c.z, x[4*i+2].y, b0);
                a1 = fmaf(c.w, x[4*i+3].x, a1);  b1 = fmaf(c.w, x[4*i+3].y, b1);
            }
            float sa = eA - (a0 + a1);
            float sb = eA - (b0 + b1);
            if (sa < v1a)      { v2a = v1a; s2a = s1a; v1a = sa; s1a = s; }
            else if (sa < v2a) { v2a = sa; s2a = s; }
            if (sb < v1b)      { v2b = v1b; s2b = s1b; v1b = sb; s1b = s; }
            else if (sb < v2b) { v2b = sb; s2b = s; }
        }

        // prefetch codeword s+2 into A (clamped dummy on last iteration)
        const int sn = (s + 2 < S) ? (s + 2) : 0;
        const float4* pA = cb4 + sn * 10;
        #pragma unroll
        for (int i = 0; i < 10; ++i) A[i] = pA[i];
        eA = e2g[sn];

        // compute with B (codeword s+1)
        {
            float a0 = 0.f, a1 = 0.f, b0 = 0.f, b1 = 0.f;
            #pragma unroll
            for (int i = 0; i < 10; ++i) {
                float4 c = B[i];
                a0 = fmaf(c.x, x[4*i+0].x, a0);  b0 = fmaf(c.x, x[4*i+0].y, b0);
                a1 = fmaf(c.y, x[4*i+1].x, a1);  b1 = fmaf(c.y, x[4*i+1].y, b1);
                a0 = fmaf(c.z, x[4*i+2].x, a0);  b0 = fmaf(c.z, x[4*i+2].y, b0);
                a1 = fmaf(c.w, x[4*i+3].x, a1);  b1 = fmaf(c.w, x[4*i+3].y, b1);
            }
            float sa = eB - (a0 + a1);
            float sb = eB - (b0 + b1);
            int si = s + 1;
            if (sa < v1a)      { v2a = v1a; s2a = s1a; v1a = sa; s1a = si; }
            else if (sa < v2a) { v2a = sa; s2a = si; }
            if (sb < v1b)      { v2b = v1b; s2b = s1b; v1b = sb; s1b = si; }
            else if (sb < v2b) { v2b = sb; s2b = si; }
        }
    }

    // fp64 recheck when fp32 gap is within rounding-uncertainty margin
    int win[2]; float v1[2], v2[2]; int sec[2];
    win[0] = s1a; sec[0] = s2a; v1[0] = v1a; v2[0] = v2a;
    win[1] = s1b; sec[1] = s2b; v1[1] = v1b; v2[1] = v2b;
    #pragma unroll
    for (int q = 0; q < 2; ++q) {
        if (v2[q] - v1[q] < 1e-3f) {
            const float* c1 = cb + ((size_t)g * S + win[q]) * K;
            const float* c2 = cb + ((size_t)g * S + sec[q]) * K;
            double t1 = 0.0, t2 = 0.0, e1 = 0.0, e2 = 0.0;
            #pragma unroll
            for (int k = 0; k < K; ++k) {
                double xk = (q == 0) ? (double)x[k].x : (double)x[k].y;
                double a  = (double)c1[k];
                double bb = (double)c2[k];
                t1 = fma(a,  xk, t1);  e1 = fma(a,  a,  e1);
                t2 = fma(bb, xk, t2);  e2 = fma(bb, bb, e2);
            }
            double sc1 = 0.5 * e1 - t1;
            double sc2 = 0.5 * e2 - t2;
            if (sc2 < sc1 || (sc2 == sc1 && sec[q] < win[q])) win[q] = sec[q];
        }
    }

    // gather winning codewords -> output (coalesced float2); fp64 loss partials
    const float* cw0 = cb + ((size_t)g * S + win[0]) * K;
    const float* cw1 = cb + ((size_t)g * S + win[1]) * K;
    float2* op2 = reinterpret_cast<float2*>(
        out + (size_t)n * CT + (size_t)g * K * TP + tp);
    double lsum = 0.0;
    #pragma unroll
    for (int k = 0; k < K; ++k) {
        float q0 = cw0[k];
        float q1 = cw1[k];
        op2[k * (TP / 2)] = make_float2(q0, q1);
        double d0 = (double)q0 - (double)x[k].x;
        double d1 = (double)q1 - (double)x[k].y;
        lsum = fma(d0, d0, lsum);
        lsum = fma(d1, d1, lsum);
    }

    if (g == 2) {
        red[threadIdx.x] = lsum;
        __syncthreads();
        for (int off = 128; off > 0; off >>= 1) {
            if (threadIdx.x < off) red[threadIdx.x] += red[threadIdx.x + off];
            __syncthreads();
        }
        if (threadIdx.x == 0) atomicAdd(loss, red[0]);
    }
}

// ---------------- finalize: scalar loss
__global__ void vq_fin_kernel(const double* __restrict__ loss, float* __restrict__ out) {
    out[OUT_Q] = (float)(0.25 * (*loss) / (double)((long long)M * K));
}

extern "C" void kernel_launch(void* const* d_in, const int* in_sizes, int n_in,
                              void* d_out, int out_size, void* d_ws, size_t ws_size,
                              hipStream_t stream) {
    const float* z  = (const float*)d_in[0];
    const float* cb = (const float*)d_in[1];
    float* out = (float*)d_out;

    double* loss = (double*)d_ws;
    float*  e2h  = (float*)((char*)d_ws + 64);

    vq_prep_kernel<<<dim3((G * S + 255) / 256), dim3(256), 0, stream>>>(cb, e2h, loss);
    vq_main_kernel<<<dim3(G * (M / 512)), dim3(256), 0, stream>>>(z, cb, e2h, out, loss);
    vq_fin_kernel<<<dim3(1), dim3(1), 0, stream>>>(loss, out);
}